// Round 4
// baseline (47.256 us; speedup 1.0000x reference)
//
#include <hip/hip_runtime.h>

#define L_SEQ 2048
#define HEADS 16
#define DIM   64
#define TILE  64
#define XROWS 66          // x rows staged: l0-1 .. l0+64
#define XPITCH 68         // f32 pitch (272B)
#define DROWS 80          // delta/E rows padded to 5 M-tiles of 16

typedef __attribute__((ext_vector_type(8))) short bf16x8;
typedef __attribute__((ext_vector_type(4))) float f32x4;

static __device__ __forceinline__ unsigned short f2bf_rtne(float f) {
    unsigned int u = __builtin_bit_cast(unsigned int, f);
    u += 0x7fffu + ((u >> 16) & 1u);
    return (unsigned short)(u >> 16);
}
// pack hi16(a) | hi16(b)<<16 in ONE v_perm_b32 (truncation rounding — error
// budget on the score path is ~1000x the threshold sensitivity)
static __device__ __forceinline__ unsigned int pk2(float a, float b) {
    return __builtin_amdgcn_perm(__builtin_bit_cast(unsigned int, b),
                                 __builtin_bit_cast(unsigned int, a), 0x07060302u);
}
static __device__ __forceinline__ unsigned short f2bf_trunc(float f) {
    return (unsigned short)(__builtin_bit_cast(unsigned int, f) >> 16);
}

// bf16 LDS tiles have 64-ushort (128B) rows -> 16-way conflict unswizzled.
// XOR-swizzle: ushort_col ^ ((row&7)<<3)  == byte ^ ((row&7)<<4).
#define SWZ(row, col) ((row) * 64 + ((col) ^ (((row) & 7) * 8)))

__global__ void prep_w_kernel(const float* __restrict__ W, unsigned short* __restrict__ wbf) {
    int i = blockIdx.x * 256 + threadIdx.x;
    if (i < DIM * DIM) wbf[i] = f2bf_rtne(W[i]);
}

static __device__ __forceinline__ bf16x8 load_bfrag(const unsigned short* wbf,
                                                    const float* W, int n, int k0) {
    if (wbf) return *(const bf16x8*)(wbf + n * 64 + k0);
    const float* wr = W + n * 64 + k0;
    float4 w0 = *(const float4*)wr;
    float4 w1 = *(const float4*)(wr + 4);
    uint4 p;
    p.x = pk2(w0.x, w0.y); p.y = pk2(w0.z, w0.w);
    p.z = pk2(w1.x, w1.y); p.w = pk2(w1.z, w1.w);
    return __builtin_bit_cast(bf16x8, p);
}

// One block = (b, h, 64 consecutive l). 512 threads = 8 waves.
__global__ __launch_bounds__(512) void betweenness_rope_kernel(
    const float* __restrict__ x, const float* __restrict__ W,
    const unsigned short* __restrict__ wbf, const float* __restrict__ gate,
    float* __restrict__ out)
{
    __shared__ float xs[XROWS * XPITCH];          // staged x rows (f32)
    __shared__ unsigned short dl[DROWS * 64];     // bf16 delta rows, swizzled
    __shared__ unsigned short el[DROWS * 64];     // bf16 E rows, swizzled
    __shared__ float n1s[65];                     // ||D_r||^2, r=0..64
    __shared__ float g1s[64];                     // D_r . D_{r+1}, r=0..63
    __shared__ float2 fl[TILE];                   // per-row {floor(adj_pos), frac}

    const int tid  = threadIdx.x;
    const int lane = tid & 63;
    const int wave = tid >> 6;
    const int la   = lane & 15, lg = lane >> 4;
    const int l0   = blockIdx.x * TILE;
    const int h    = blockIdx.y;
    const int b    = blockIdx.z;
    const int bh_off = (b * L_SEQ * HEADS + h) * DIM;

    // ---- Phase 1: stage x rows (x read from HBM exactly once) ----
    for (int c = tid; c < XROWS * 16; c += 512) {
        int r = c >> 4, q = c & 15;
        int g = l0 - 1 + r; g = max(0, min(L_SEQ - 1, g));
        float4 v = *(const float4*)(x + bh_off + g * (HEADS * DIM) + q * 4);
        *(float4*)&xs[r * XPITCH + q * 4] = v;
    }
    __syncthreads();

    // ---- Phase 2: delta rows dl[r] = bf16(xs[r+1] - xs[r]), r=0..64; 65..79 zero ----
    for (int c = tid; c < DROWS * 8; c += 512) {
        int r = c >> 3, c0 = (c & 7) * 8;
        uint4 o = {0u, 0u, 0u, 0u};
        if (r <= 64) {
            float4 a0 = *(float4*)&xs[r * XPITCH + c0];
            float4 a1 = *(float4*)&xs[r * XPITCH + c0 + 4];
            float4 b0 = *(float4*)&xs[(r + 1) * XPITCH + c0];
            float4 b1 = *(float4*)&xs[(r + 1) * XPITCH + c0 + 4];
            o.x = pk2(b0.x - a0.x, b0.y - a0.y);
            o.y = pk2(b0.z - a0.z, b0.w - a0.w);
            o.z = pk2(b1.x - a1.x, b1.y - a1.y);
            o.w = pk2(b1.z - a1.z, b1.w - a1.w);
        }
        *(uint4*)&dl[SWZ(r, c0)] = o;
    }
    __syncthreads();

    // ---- Phase 3: E = Delta @ W^T via MFMA (20 16x16 tile-jobs over 8 waves) ----
    for (int job = wave; job < 20; job += 8) {
        int mt = job >> 2, nt = job & 3;
        bf16x8 a0 = *(const bf16x8*)&dl[SWZ(16 * mt + la, lg * 8)];
        bf16x8 a1 = *(const bf16x8*)&dl[SWZ(16 * mt + la, lg * 8 + 32)];
        bf16x8 b0 = load_bfrag(wbf, W, 16 * nt + la, lg * 8);
        bf16x8 b1 = load_bfrag(wbf, W, 16 * nt + la, lg * 8 + 32);
        f32x4 acc = {0.f, 0.f, 0.f, 0.f};
        acc = __builtin_amdgcn_mfma_f32_16x16x32_bf16(a0, b0, acc, 0, 0, 0);
        acc = __builtin_amdgcn_mfma_f32_16x16x32_bf16(a1, b1, acc, 0, 0, 0);
        #pragma unroll
        for (int q = 0; q < 4; ++q)   // D layout: col=lane&15, row=(lane>>4)*4+q
            el[SWZ(16 * mt + lg * 4 + q, 16 * nt + la)] = f2bf_trunc(acc[q]);
    }
    __syncthreads();

    // ---- Phase 4: Gram band via MFMA: 5 diag + 4 superdiag tile-jobs ----
    for (int job = wave; job < 9; job += 8) {
        int mt = (job < 5) ? job : job - 5;
        int nt = (job < 5) ? job : job - 4;
        f32x4 g = {0.f, 0.f, 0.f, 0.f};
        #pragma unroll
        for (int kt = 0; kt < 2; ++kt) {
            int cb = lg * 8 + kt * 32;
            bf16x8 a  = *(const bf16x8*)&el[SWZ(16 * mt + la, cb)];
            bf16x8 bb = *(const bf16x8*)&el[SWZ(16 * nt + la, cb)];  // B[k][n]=E[n][k]
            g = __builtin_amdgcn_mfma_f32_16x16x32_bf16(a, bb, g, 0, 0, 0);
        }
        #pragma unroll
        for (int q = 0; q < 4; ++q) {
            int R = 16 * mt + lg * 4 + q, C = 16 * nt + la;
            if (C == R && R < 65) n1s[R] = g[q];
            if (C == R + 1 && R < 64) g1s[R] = g[q];
        }
    }
    __syncthreads();

    // ---- Phase 5: per-row score -> (flo, frac), computed once (64 threads) ----
    if (tid < TILE) {
        const float gate0 = gate[0];
        int r = tid, l = l0 + r;
        float a1 = n1s[r], b1 = n1s[r + 1], gg = g1s[r];
        float d1a = sqrtf(a1), d1b = sqrtf(b1);
        float dd  = sqrtf(fmaxf(a1 + b1 + 2.f * gg, 0.f));   // ||D_r + D_{r+1}||
        float sc  = fmaxf(1.f - ((d1a + d1b) - dd) / fmaxf(dd, 1e-6f), 0.f);
        float bet = (l >= 1 && l <= L_SEQ - 2) ? sc * (1.f / (L_SEQ - 2)) : 0.f;
        float adjust = gate0 * (bet - 0.5f) * 0.1f;
        float ap  = fminf(fmaxf((float)l + adjust, 0.f), (float)(L_SEQ - 1));
        float flo = floorf(ap);
        fl[r] = make_float2(flo, ap - flo);
    }
    __syncthreads();

    // ---- Phase 6: RoPE epilogue: 1 sincos + angle-addition rotation ----
    {
        const int j = lane & 31, half = lane >> 5;
        // fjr = f_j / (2*pi): revolutions per position; f_j = 10000^(-j/32)
        const float fjr = __builtin_exp2f(-0.4152410118609203f * (float)j)
                        * 0.15915494309189535f;
        const float cf = __builtin_amdgcn_cosf(fjr);
        const float sf = __builtin_amdgcn_sinf(fjr);
        const float cfm1 = cf - 1.0f;
        const int r0w = wave * 2 + half;               // base row 0..15
        const float* xbase = &xs[(r0w + 1) * XPITCH + 2 * j];
        float* obase = out + bh_off + (l0 + r0w) * (HEADS * DIM) + 2 * j;
        #pragma unroll
        for (int it = 0; it < 4; ++it) {
            int r = it * 16 + r0w;
            float2 ff = fl[r];
            float t0 = ff.x * fjr;                     // revolutions at lo
            float rv = t0 - floorf(t0);
            float c_lo = __builtin_amdgcn_cosf(rv);
            float s_lo = __builtin_amdgcn_sinf(rv);
            float u = fmaf(ff.y, cfm1, 1.0f);          // (1-frac) + frac*cf
            float v = ff.y * sf;                       // frac*sf
            float ci = fmaf(-s_lo, v, c_lo * u);       // interp cos
            float si = fmaf(c_lo, v, s_lo * u);        // interp sin
            float2 xv = *(const float2*)(xbase + it * 16 * XPITCH);
            float2 o;
            o.x = xv.x * ci - xv.y * si;
            o.y = fmaf(xv.y, ci, xv.x * si);
            *(float2*)(obase + it * 16 * (HEADS * DIM)) = o;
        }
    }
}

extern "C" void kernel_launch(void* const* d_in, const int* in_sizes, int n_in,
                              void* d_out, int out_size, void* d_ws, size_t ws_size,
                              hipStream_t stream) {
    const float* x    = (const float*)d_in[0];
    const float* W    = (const float*)d_in[1];
    const float* gate = (const float*)d_in[3];   // bias cancels in differences
    float* out = (float*)d_out;

    const int B = in_sizes[0] / (L_SEQ * HEADS * DIM);

    unsigned short* wbf = nullptr;
    if (ws_size >= (size_t)(DIM * DIM * sizeof(unsigned short))) {
        wbf = (unsigned short*)d_ws;
        prep_w_kernel<<<16, 256, 0, stream>>>(W, wbf);
    }

    dim3 grid(L_SEQ / TILE, HEADS, B);
    betweenness_rope_kernel<<<grid, 512, 0, stream>>>(x, W, wbf, gate, out);
}